// Round 3
// baseline (1552.206 us; speedup 1.0000x reference)
//
#include <hip/hip_runtime.h>

typedef short bf16x8 __attribute__((ext_vector_type(8)));
typedef float f32x4 __attribute__((ext_vector_type(4)));

__device__ __forceinline__ float bf2f(short b) {
  return __uint_as_float(((unsigned)(unsigned short)b) << 16);
}
__device__ __forceinline__ short f2bf(float f) {
  unsigned u = __float_as_uint(f);
  u = u + 0x7FFF + ((u >> 16) & 1);  // RNE; inputs finite
  return (short)(u >> 16);
}
__device__ __forceinline__ short f2h(float f) {
  _Float16 h = (_Float16)f;
  return __builtin_bit_cast(short, h);
}
__device__ __forceinline__ float h2f(short s) {
  return (float)__builtin_bit_cast(_Float16, s);
}

__device__ __forceinline__ void gload16(const void* g, void* lds) {
  __builtin_amdgcn_global_load_lds(
      (const __attribute__((address_space(1))) unsigned*)g,
      (__attribute__((address_space(3))) unsigned*)lds, 16, 0, 0);
}

#define BM 128
#define BN 128
#define BK 32

// C[M,N] = A[M,K] @ B[N,K]^T, bf16 row-major, K contiguous.
// ASPLIT/BSPLIT: operand has hi+lo bf16 pair -> 3-term split-precision MFMA.
// OMODE: 0=f32 out, 1=bf16 out, 2=bf16 hi/lo pair out, 3=f16 out.
// BIAS_MODE: 0=none, 1=bias[col], 2=bias[row]. RES: add fp32 resid[idx].
template <int ASPLIT, int BSPLIT, int OMODE, int BIAS_MODE, int RES>
__global__ __launch_bounds__(256, 2) void gemm_bt(
    const short* __restrict__ A, const short* __restrict__ Al, int lda,
    const short* __restrict__ B, const short* __restrict__ Bl, int ldb,
    void* __restrict__ Cv, short* __restrict__ Clo, int ldc,
    const float* __restrict__ bias, const float* __restrict__ resid, int K) {
  constexpr int NBUF = 2 + ASPLIT + BSPLIT;
  __shared__ short lds[NBUF * 4096];
  short* Ash = lds;
  short* Asl = lds + (ASPLIT ? 4096 : 0);
  short* Bsh = lds + (1 + ASPLIT) * 4096;
  short* Bsl = Bsh + 4096;

  const int tid = threadIdx.x;
  const int wid = tid >> 6, lane = tid & 63;
  const int wr = wid >> 1, wc = wid & 1;
  const int fr = lane & 15, fq = lane >> 4;
  const size_t bm = (size_t)blockIdx.y * BM;
  const size_t bn = (size_t)blockIdx.x * BN;

  const int r0 = tid >> 2;        // row within tile half (0..63)
  const int k0 = (tid & 3) << 3;  // k elem offset (8 per 16B)

  const size_t aoff = (bm + r0) * (size_t)lda + k0;
  const size_t boff = (bn + r0) * (size_t)ldb + k0;
  char* AshW = (char*)Ash + wid * 1024;  // wave-uniform LDS bases
  char* AslW = (char*)Asl + wid * 1024;
  char* BshW = (char*)Bsh + wid * 1024;
  char* BslW = (char*)Bsl + wid * 1024;

  f32x4 acc[4][4];
#pragma unroll
  for (int m = 0; m < 4; m++)
#pragma unroll
    for (int n = 0; n < 4; n++) acc[m][n] = (f32x4){0.f, 0.f, 0.f, 0.f};

  for (int kt = 0; kt < K; kt += BK) {
    gload16(A + aoff + kt, AshW);
    gload16(A + aoff + kt + (size_t)64 * lda, AshW + 4096);
    gload16(B + boff + kt, BshW);
    gload16(B + boff + kt + (size_t)64 * ldb, BshW + 4096);
    if (ASPLIT) {
      gload16(Al + aoff + kt, AslW);
      gload16(Al + aoff + kt + (size_t)64 * lda, AslW + 4096);
    }
    if (BSPLIT) {
      gload16(Bl + boff + kt, BslW);
      gload16(Bl + boff + kt + (size_t)64 * ldb, BslW + 4096);
    }
    __syncthreads();  // compiler drains vmcnt before barrier
    bf16x8 ah[4], bh[4];
#pragma unroll
    for (int m = 0; m < 4; m++)
      ah[m] = *(const bf16x8*)(Ash + (wr * 64 + m * 16 + fr) * BK + fq * 8);
#pragma unroll
    for (int n = 0; n < 4; n++)
      bh[n] = *(const bf16x8*)(Bsh + (wc * 64 + n * 16 + fr) * BK + fq * 8);
#pragma unroll
    for (int m = 0; m < 4; m++)
#pragma unroll
      for (int n = 0; n < 4; n++)
        acc[m][n] = __builtin_amdgcn_mfma_f32_16x16x32_bf16(ah[m], bh[n],
                                                            acc[m][n], 0, 0, 0);
    if (BSPLIT) {
      bf16x8 bl[4];
#pragma unroll
      for (int n = 0; n < 4; n++)
        bl[n] = *(const bf16x8*)(Bsl + (wc * 64 + n * 16 + fr) * BK + fq * 8);
#pragma unroll
      for (int m = 0; m < 4; m++)
#pragma unroll
        for (int n = 0; n < 4; n++)
          acc[m][n] = __builtin_amdgcn_mfma_f32_16x16x32_bf16(ah[m], bl[n],
                                                              acc[m][n], 0, 0, 0);
    }
    if (ASPLIT) {
      bf16x8 al[4];
#pragma unroll
      for (int m = 0; m < 4; m++)
        al[m] = *(const bf16x8*)(Asl + (wr * 64 + m * 16 + fr) * BK + fq * 8);
#pragma unroll
      for (int m = 0; m < 4; m++)
#pragma unroll
        for (int n = 0; n < 4; n++)
          acc[m][n] = __builtin_amdgcn_mfma_f32_16x16x32_bf16(al[m], bh[n],
                                                              acc[m][n], 0, 0, 0);
    }
    __syncthreads();
  }

#pragma unroll
  for (int m = 0; m < 4; m++) {
    const size_t row0 = bm + wr * 64 + m * 16 + fq * 4;
#pragma unroll
    for (int n = 0; n < 4; n++) {
      const size_t col = bn + wc * 64 + n * 16 + fr;
#pragma unroll
      for (int r = 0; r < 4; r++) {
        float val = acc[m][n][r];
        const size_t row = row0 + r;
        const size_t idx = row * (size_t)ldc + col;
        if (BIAS_MODE == 1) val += bias[col];
        if (BIAS_MODE == 2) val += bias[row];
        if (RES) val += resid[idx];
        if (OMODE == 0) {
          ((float*)Cv)[idx] = val;
        } else if (OMODE == 1) {
          ((short*)Cv)[idx] = f2bf(val);
        } else if (OMODE == 2) {
          short h = f2bf(val);
          ((short*)Cv)[idx] = h;
          Clo[idx] = f2bf(val - bf2f(h));
        } else {
          ((short*)Cv)[idx] = f2h(val);
        }
      }
    }
  }
}

__global__ __launch_bounds__(256) void cvt_f32_bf16(const float* __restrict__ s,
                                                    short* __restrict__ d, int n) {
  int i = (blockIdx.x * 256 + threadIdx.x) * 8;
  if (i >= n) return;
  const float4 a = *(const float4*)(s + i);
  const float4 b = *(const float4*)(s + i + 4);
  bf16x8 o;
  o[0] = f2bf(a.x); o[1] = f2bf(a.y); o[2] = f2bf(a.z); o[3] = f2bf(a.w);
  o[4] = f2bf(b.x); o[5] = f2bf(b.y); o[6] = f2bf(b.z); o[7] = f2bf(b.w);
  *(bf16x8*)(d + i) = o;
}

__global__ __launch_bounds__(256) void cvt_split(const float* __restrict__ s,
                                                 short* __restrict__ hi,
                                                 short* __restrict__ lo, int n) {
  int i = (blockIdx.x * 256 + threadIdx.x) * 8;
  if (i >= n) return;
  const float4 a = *(const float4*)(s + i);
  const float4 b = *(const float4*)(s + i + 4);
  float v[8] = {a.x, a.y, a.z, a.w, b.x, b.y, b.z, b.w};
  bf16x8 h, l;
#pragma unroll
  for (int j = 0; j < 8; j++) {
    short hb = f2bf(v[j]);
    h[j] = hb;
    l[j] = f2bf(v[j] - bf2f(hb));
  }
  *(bf16x8*)(hi + i) = h;
  *(bf16x8*)(lo + i) = l;
}

// one block per row of 4096 f16 scores; fp32 softmax; in-place bf16 probs
__global__ __launch_bounds__(256) void softmax_rows(short* __restrict__ S) {
  const size_t row = blockIdx.x;
  short* rp = S + row * 4096;
  const int tid = threadIdx.x;
  const int lane = tid & 63, wid = tid >> 6;
  float v[16];
#pragma unroll
  for (int c = 0; c < 2; c++) {
    bf16x8 xv = *(const bf16x8*)(rp + (c * 256 + tid) * 8);
#pragma unroll
    for (int j = 0; j < 8; j++) v[c * 8 + j] = h2f(xv[j]);
  }
  float m = v[0];
#pragma unroll
  for (int i = 1; i < 16; i++) m = fmaxf(m, v[i]);
#pragma unroll
  for (int off = 32; off >= 1; off >>= 1) m = fmaxf(m, __shfl_xor(m, off));
  __shared__ float red[8];
  if (lane == 0) red[wid] = m;
  __syncthreads();
  m = fmaxf(fmaxf(red[0], red[1]), fmaxf(red[2], red[3]));
  float s = 0.f;
#pragma unroll
  for (int i = 0; i < 16; i++) {
    v[i] = __expf(v[i] - m);
    s += v[i];
  }
#pragma unroll
  for (int off = 32; off >= 1; off >>= 1) s += __shfl_xor(s, off);
  if (lane == 0) red[4 + wid] = s;
  __syncthreads();
  s = (red[4] + red[5]) + (red[6] + red[7]);
  const float rs = 1.0f / s;
#pragma unroll
  for (int c = 0; c < 2; c++) {
    bf16x8 o;
#pragma unroll
    for (int j = 0; j < 8; j++) o[j] = f2bf(v[c * 8 + j] * rs);
    *(bf16x8*)(rp + (c * 256 + tid) * 8) = o;
  }
}

extern "C" void kernel_launch(void* const* d_in, const int* in_sizes, int n_in,
                              void* d_out, int out_size, void* d_ws,
                              size_t ws_size, hipStream_t stream) {
  const float* x   = (const float*)d_in[0];
  const float* thw = (const float*)d_in[1];
  const float* thb = (const float*)d_in[2];
  const float* phw = (const float*)d_in[3];
  const float* phb = (const float*)d_in[4];
  const float* gw  = (const float*)d_in[5];
  const float* gbi = (const float*)d_in[6];
  const float* Ww  = (const float*)d_in[7];
  const float* Wb  = (const float*)d_in[8];
  float* out = (float*)d_out;

  // B=4, N=4096, D=2048, E=1024 — everything per-batch; ws total ~143 MB
  char* ws = (char*)d_ws;
  short* wch = (short*)(ws);              // theta|phi weights hi, 2048x2048
  short* wcl = (short*)(ws + 8388608);    // lo
  short* gwb = (short*)(ws + 16777216);   // g_w bf16, 1024x2048
  short* wWb = (short*)(ws + 20971520);   // W_w bf16, 2048x1024
  float* bc  = (float*)(ws + 25165824);   // theta_b|phi_b, 2048 f32
  short* xh  = (short*)(ws + 25174016);   // x_b hi, 4096x2048
  short* xl  = (short*)(ws + 41951232);   // x_b lo
  short* tph = (short*)(ws + 58728448);   // theta|phi hi, 4096x2048
  short* tpl = (short*)(ws + 75505664);   // lo
  short* gT  = (short*)(ws + 92282880);   // gT_b bf16, 1024x4096
  short* sc  = (short*)(ws + 100671488);  // scores f16 -> probs bf16, 4096x4096
  short* yb  = (short*)(ws + 134225920);  // y_b bf16, 4096x1024

  // weights: split for theta|phi, plain bf16 for g and W
  cvt_split<<<1024, 256, 0, stream>>>(thw, wch, wcl, 2097152);
  cvt_split<<<1024, 256, 0, stream>>>(phw, wch + 2097152, wcl + 2097152, 2097152);
  cvt_f32_bf16<<<1024, 256, 0, stream>>>(gw, gwb, 2097152);
  cvt_f32_bf16<<<1024, 256, 0, stream>>>(Ww, wWb, 2097152);
  hipMemcpyAsync(bc, thb, 4096, hipMemcpyDeviceToDevice, stream);
  hipMemcpyAsync(bc + 1024, phb, 4096, hipMemcpyDeviceToDevice, stream);

  for (int b = 0; b < 4; b++) {
    const float* xb = x + (size_t)b * 8388608;
    cvt_split<<<4096, 256, 0, stream>>>(xb, xh, xl, 8388608);
    // [theta|phi] = x_b @ wcat^T + bias  (4096x2048, K=2048, 3-term split)
    gemm_bt<1, 1, 2, 1, 0><<<dim3(16, 32), 256, 0, stream>>>(
        xh, xl, 2048, wch, wcl, 2048, tph, tpl, 2048, bc, nullptr, 2048);
    // gT_b = g_w @ x_b^T + g_b[row]  (1024x4096, K=2048)
    gemm_bt<0, 0, 1, 2, 0><<<dim3(32, 8), 256, 0, stream>>>(
        gwb, nullptr, 2048, xh, nullptr, 2048, gT, nullptr, 4096, gbi, nullptr,
        2048);
    // scores = theta @ phi^T  (4096x4096, K=1024, 3-term split, f16 out)
    gemm_bt<1, 1, 3, 0, 0><<<dim3(32, 32), 256, 0, stream>>>(
        tph, tpl, 2048, tph + 1024, tpl + 1024, 2048, sc, nullptr, 4096,
        nullptr, nullptr, 1024);
    softmax_rows<<<4096, 256, 0, stream>>>(sc);
    // y_b = probs @ gT^T  (4096x1024, K=4096)
    gemm_bt<0, 0, 1, 0, 0><<<dim3(8, 32), 256, 0, stream>>>(
        sc, nullptr, 4096, gT, nullptr, 4096, yb, nullptr, 1024, nullptr,
        nullptr, 4096);
    // z_b = y_b @ W_w^T + W_b + x_b  (4096x2048 f32, K=1024)
    gemm_bt<0, 0, 0, 1, 1><<<dim3(16, 32), 256, 0, stream>>>(
        yb, nullptr, 1024, wWb, nullptr, 1024, out + (size_t)b * 8388608,
        nullptr, 2048, Wb, xb, 1024);
  }
}

// Round 5
// 968.576 us; speedup vs baseline: 1.6026x; 1.6026x over previous
//
#include <hip/hip_runtime.h>

typedef short bf16x8 __attribute__((ext_vector_type(8)));
typedef _Float16 f16x8 __attribute__((ext_vector_type(8)));
typedef float f32x4 __attribute__((ext_vector_type(4)));

__device__ __forceinline__ short f2h(float f) {
  _Float16 h = (_Float16)f;
  return __builtin_bit_cast(short, h);
}
__device__ __forceinline__ float h2f(short s) {
  return (float)__builtin_bit_cast(_Float16, s);
}

__device__ __forceinline__ void gload16(const void* g, void* lds) {
  __builtin_amdgcn_global_load_lds(
      (const __attribute__((address_space(1))) unsigned*)g,
      (__attribute__((address_space(3))) unsigned*)lds, 16, 0, 0);
}

#define BM 128
#define BN 128
#define BK 32

// C[M,N] = A[M,K] @ B[N,K]^T, f16 row-major, K contiguous.
// OMODE: 0=f32 out, 1=f16 out.
// BIAS_MODE: 0=none, 1=bias[col], 2=bias[row]. RES: add fp32 resid[idx].
template <int OMODE, int BIAS_MODE, int RES>
__global__ __launch_bounds__(256, 2) void gemm_bt(
    const short* __restrict__ A, int lda, long sA,
    const short* __restrict__ B, int ldb, long sB,
    void* __restrict__ Cv, int ldc, long sC,
    const float* __restrict__ bias, const float* __restrict__ resid, int K) {
  A += (size_t)blockIdx.z * sA;
  B += (size_t)blockIdx.z * sB;
  char* Cbase = (char*)Cv + (size_t)blockIdx.z * sC * (OMODE == 0 ? 4 : 2);

  __shared__ short As[BM * BK];
  __shared__ short Bs[BN * BK];
  const int tid = threadIdx.x;
  const int wid = tid >> 6, lane = tid & 63;
  const int wr = wid >> 1, wc = wid & 1;
  const int fr = lane & 15, fq = lane >> 4;
  const size_t bm = (size_t)blockIdx.y * BM;
  const size_t bn = (size_t)blockIdx.x * BN;

  const int r0 = tid >> 2;        // row within tile half (0..63)
  const int k0 = (tid & 3) << 3;  // k elem offset (8 per 16B)

  const size_t aoff = (bm + r0) * (size_t)lda + k0;
  const size_t boff = (bn + r0) * (size_t)ldb + k0;
  char* AsW = (char*)As + wid * 1024;  // wave-uniform LDS bases
  char* BsW = (char*)Bs + wid * 1024;

  f32x4 acc[4][4];
#pragma unroll
  for (int m = 0; m < 4; m++)
#pragma unroll
    for (int n = 0; n < 4; n++) acc[m][n] = (f32x4){0.f, 0.f, 0.f, 0.f};

  for (int kt = 0; kt < K; kt += BK) {
    gload16(A + aoff + kt, AsW);
    gload16(A + aoff + kt + (size_t)64 * lda, AsW + 4096);
    gload16(B + boff + kt, BsW);
    gload16(B + boff + kt + (size_t)64 * ldb, BsW + 4096);
    __syncthreads();  // compiler drains vmcnt before barrier
    f16x8 af[4], bfr[4];
#pragma unroll
    for (int m = 0; m < 4; m++)
      af[m] = *(const f16x8*)(As + (wr * 64 + m * 16 + fr) * BK + fq * 8);
#pragma unroll
    for (int n = 0; n < 4; n++)
      bfr[n] = *(const f16x8*)(Bs + (wc * 64 + n * 16 + fr) * BK + fq * 8);
#pragma unroll
    for (int m = 0; m < 4; m++)
#pragma unroll
      for (int n = 0; n < 4; n++)
        acc[m][n] = __builtin_amdgcn_mfma_f32_16x16x32_f16(af[m], bfr[n],
                                                           acc[m][n], 0, 0, 0);
    __syncthreads();
  }

#pragma unroll
  for (int m = 0; m < 4; m++) {
    const size_t row0 = bm + wr * 64 + m * 16 + fq * 4;
#pragma unroll
    for (int n = 0; n < 4; n++) {
      const size_t col = bn + wc * 64 + n * 16 + fr;
#pragma unroll
      for (int r = 0; r < 4; r++) {
        float val = acc[m][n][r];
        const size_t row = row0 + r;
        const size_t idx = row * (size_t)ldc + col;
        if (BIAS_MODE == 1) val += bias[col];
        if (BIAS_MODE == 2) val += bias[row];
        if (RES) val += resid[idx];
        if (OMODE == 0)
          ((float*)Cbase)[idx] = val;
        else
          ((short*)Cbase)[idx] = f2h(val);
      }
    }
  }
}

__global__ __launch_bounds__(256) void cvt_f32_f16(const float* __restrict__ s,
                                                   short* __restrict__ d, int n) {
  int i = (blockIdx.x * 256 + threadIdx.x) * 8;
  if (i >= n) return;
  const float4 a = *(const float4*)(s + i);
  const float4 b = *(const float4*)(s + i + 4);
  bf16x8 o;
  o[0] = f2h(a.x); o[1] = f2h(a.y); o[2] = f2h(a.z); o[3] = f2h(a.w);
  o[4] = f2h(b.x); o[5] = f2h(b.y); o[6] = f2h(b.z); o[7] = f2h(b.w);
  *(bf16x8*)(d + i) = o;
}

// one block per row of 4096 f16 scores; fp32 softmax; in-place f16 probs
__global__ __launch_bounds__(256) void softmax_rows(short* __restrict__ S) {
  const size_t row = blockIdx.x;
  short* rp = S + row * 4096;
  const int tid = threadIdx.x;
  const int lane = tid & 63, wid = tid >> 6;
  float v[16];
#pragma unroll
  for (int c = 0; c < 2; c++) {
    bf16x8 xv = *(const bf16x8*)(rp + (c * 256 + tid) * 8);
#pragma unroll
    for (int j = 0; j < 8; j++) v[c * 8 + j] = h2f(xv[j]);
  }
  float m = v[0];
#pragma unroll
  for (int i = 1; i < 16; i++) m = fmaxf(m, v[i]);
#pragma unroll
  for (int off = 32; off >= 1; off >>= 1) m = fmaxf(m, __shfl_xor(m, off));
  __shared__ float red[8];
  if (lane == 0) red[wid] = m;
  __syncthreads();
  m = fmaxf(fmaxf(red[0], red[1]), fmaxf(red[2], red[3]));
  float s = 0.f;
#pragma unroll
  for (int i = 0; i < 16; i++) {
    v[i] = __expf(v[i] - m);
    s += v[i];
  }
#pragma unroll
  for (int off = 32; off >= 1; off >>= 1) s += __shfl_xor(s, off);
  if (lane == 0) red[4 + wid] = s;
  __syncthreads();
  s = (red[4] + red[5]) + (red[6] + red[7]);
  const float rs = 1.0f / s;
#pragma unroll
  for (int c = 0; c < 2; c++) {
    bf16x8 o;
#pragma unroll
    for (int j = 0; j < 8; j++) o[j] = f2h(v[c * 8 + j] * rs);
    *(bf16x8*)(rp + (c * 256 + tid) * 8) = o;
  }
}

extern "C" void kernel_launch(void* const* d_in, const int* in_sizes, int n_in,
                              void* d_out, int out_size, void* d_ws,
                              size_t ws_size, hipStream_t stream) {
  const float* x   = (const float*)d_in[0];
  const float* thw = (const float*)d_in[1];
  const float* thb = (const float*)d_in[2];
  const float* phw = (const float*)d_in[3];
  const float* phb = (const float*)d_in[4];
  const float* gw  = (const float*)d_in[5];
  const float* gbi = (const float*)d_in[6];
  const float* Ww  = (const float*)d_in[7];
  const float* Wb  = (const float*)d_in[8];
  float* out = (float*)d_out;

  // B=4, N=4096, D=2048, E=1024.  ws footprint 184,557,568 B (== round-0, ran OK)
  char* ws = (char*)d_ws;
  short* xf   = (short*)(ws);                // 67,108,864 B (16384x2048 f16)
  short* wcat = (short*)(ws + 67108864);     //  8,388,608 B (theta|phi 2048x2048)
  short* gwb  = (short*)(ws + 75497472);     //  4,194,304 B (1024x2048)
  short* wWb  = (short*)(ws + 79691776);     //  4,194,304 B (2048x1024)
  float* bc   = (float*)(ws + 83886080);     //  8,192 B (theta_b|phi_b)
  short* tpf  = (short*)(ws + 83894272);     // 67,108,864 B (16384x2048: theta|phi)
  short* gT   = (short*)(ws + 151003136);    // 33,554,432 B (4x1024x4096)
  // after proj+gT, xf region is dead -> reuse:
  short* sc   = (short*)(ws);                // 33,554,432 B (4096x4096 per batch)
  short* yb   = (short*)(ws + 33554432);     // 33,554,432 B (16384x1024)

  // 1) fp32 -> f16 conversions
  cvt_f32_f16<<<16384, 256, 0, stream>>>(x, xf, 33554432);
  cvt_f32_f16<<<1024, 256, 0, stream>>>(thw, wcat, 2097152);
  cvt_f32_f16<<<1024, 256, 0, stream>>>(phw, wcat + 2097152, 2097152);
  cvt_f32_f16<<<1024, 256, 0, stream>>>(gw, gwb, 2097152);
  cvt_f32_f16<<<1024, 256, 0, stream>>>(Ww, wWb, 2097152);
  hipMemcpyAsync(bc, thb, 4096, hipMemcpyDeviceToDevice, stream);
  hipMemcpyAsync(bc + 1024, phb, 4096, hipMemcpyDeviceToDevice, stream);

  // 2) proj: [theta|phi] = x @ wcat^T + bias   (16384 x 2048, K=2048)
  gemm_bt<1, 1, 0><<<dim3(16, 128), 256, 0, stream>>>(
      xf, 2048, 0L, wcat, 2048, 0L, tpf, 2048, 0L, bc, nullptr, 2048);

  // 3) gT[b] = g_w @ x_b^T + g_b[row]   (1024 x 4096 per batch, K=2048)
  gemm_bt<1, 2, 0><<<dim3(32, 8, 4), 256, 0, stream>>>(
      gwb, 2048, 0L, xf, 2048, 8388608L, gT, 4096, 4194304L, gbi, nullptr, 2048);

  // 4) per batch: scores -> softmax -> y   (xf now dead; sc/yb overlay it)
  for (int b = 0; b < 4; b++) {
    const short* th = tpf + (size_t)b * 4096 * 2048;
    gemm_bt<1, 0, 0><<<dim3(32, 32), 256, 0, stream>>>(
        th, 2048, 0L, th + 1024, 2048, 0L, sc, 4096, 0L, nullptr, nullptr, 1024);
    softmax_rows<<<4096, 256, 0, stream>>>(sc);
    gemm_bt<1, 0, 0><<<dim3(8, 32), 256, 0, stream>>>(
        sc, 4096, 0L, gT + (size_t)b * 4194304, 4096, 0L,
        yb + (size_t)b * 4194304, 1024, 0L, nullptr, nullptr, 4096);
  }

  // 5) z = y @ W_w^T + W_b + x   (16384 x 2048 f32 out, K=1024)
  gemm_bt<0, 1, 1><<<dim3(16, 128), 256, 0, stream>>>(
      yb, 1024, 0L, wWb, 1024, 0L, out, 2048, 0L, Wb, x, 1024);
}

// Round 6
// 716.924 us; speedup vs baseline: 2.1651x; 1.3510x over previous
//
#include <hip/hip_runtime.h>

typedef short bf16x8 __attribute__((ext_vector_type(8)));
typedef _Float16 f16x8 __attribute__((ext_vector_type(8)));
typedef float f32x4 __attribute__((ext_vector_type(4)));

__device__ __forceinline__ short f2h(float f) {
  _Float16 h = (_Float16)f;
  return __builtin_bit_cast(short, h);
}
__device__ __forceinline__ float h2f(short s) {
  return (float)__builtin_bit_cast(_Float16, s);
}

__device__ __forceinline__ void gload16(const void* g, void* lds) {
  __builtin_amdgcn_global_load_lds(
      (const __attribute__((address_space(1))) unsigned*)g,
      (__attribute__((address_space(3))) unsigned*)lds, 16, 0, 0);
}

// ---------------------------------------------------------------------------
// 256xBN tile GEMM, C = A @ B^T (f16, K contiguous), BK=64, 512 thr = 8 waves
// (2 M x 4 N). LDS double-buffered, raw s_barrier + counted vmcnt (loads for
// tile t+1 stay in flight across barriers). LDS XOR-swizzle (16B granule,
// col ^= (row&7)<<4) applied on the GLOBAL source (linear gload_lds dest) and
// on ds_read -> bank-floor access pattern (rule #21: both-sides-or-neither).
// NF: N-fragments per wave (4 -> BN=256, 2 -> BN=128).
// OMODE: 0=f32 out, 1=f16 out. BIAS_MODE: 0 none, 1 bias[col], 2 bias[row].
// RES: add fp32 resid[idx] (stride sR per blockIdx.z).
// ---------------------------------------------------------------------------
template <int NF, int K, int OMODE, int BIAS_MODE, int RES>
__global__ __launch_bounds__(512, 2) void gemm256(
    const short* __restrict__ A, int lda, long sA,
    const short* __restrict__ B, int ldb, long sB,
    void* __restrict__ Cv, int ldc, long sC,
    const float* __restrict__ bias, const float* __restrict__ resid, long sR) {
  constexpr int BN = NF * 64;
  constexpr int BNB = BN * 128;  // B-tile bytes per buffer
  constexpr int NT = K / 64;
  __shared__ char lds[65536 + 2 * BNB];  // A: 2x32KB, B: 2xBNB

  A += (size_t)blockIdx.z * sA;
  B += (size_t)blockIdx.z * sB;
  char* Cb = (char*)Cv + (size_t)blockIdx.z * sC * (OMODE == 0 ? 4 : 2);
  const float* res = resid ? resid + (size_t)blockIdx.z * sR : nullptr;

  const int tid = threadIdx.x;
  const int wid = tid >> 6, lane = tid & 63;
  const int wr = wid >> 2, wc = wid & 3;      // wave grid 2 (M) x 4 (N)
  const int fr = lane & 15, fq = lane >> 4;
  const size_t bm = (size_t)blockIdx.y * 256;
  const size_t bn = (size_t)blockIdx.x * BN;

  // staging: per chunk 64 rows x 128 B; thread covers row srow, 16 B at scolS
  const int srow = wid * 8 + (lane >> 3);          // 0..63
  const int scolS = ((lane & 7) * 16) ^ ((srow & 7) << 4);  // inv-swizzled src
  const char* Ag = (const char*)A;
  const char* Bg = (const char*)B;

  // ds_read byte offsets (ks=0, buffer 0); row&7 == fr&7 for all fragments
  const int swz = (fr & 7) << 4;
  int aoff[8], boff[NF];
#pragma unroll
  for (int m = 0; m < 8; m++)
    aoff[m] = (wr * 128 + m * 16 + fr) * 128 + ((fq * 16) ^ swz);
#pragma unroll
  for (int n = 0; n < NF; n++)
    boff[n] = (wc * NF * 16 + n * 16 + fr) * 128 + ((fq * 16) ^ swz);

  f32x4 acc[8][NF];
#pragma unroll
  for (int m = 0; m < 8; m++)
#pragma unroll
    for (int n = 0; n < NF; n++) acc[m][n] = (f32x4){0.f, 0.f, 0.f, 0.f};

  auto stage = [&](int t, int d) {
    const int ktb = t * 128;  // byte offset along K
#pragma unroll
    for (int c = 0; c < 4; ++c)
      gload16(Ag + ((size_t)(bm + c * 64 + srow) * lda) * 2 + ktb + scolS,
              &lds[d * 32768 + c * 8192 + wid * 1024]);
#pragma unroll
    for (int c = 0; c < NF; ++c)
      gload16(Bg + ((size_t)(bn + c * 64 + srow) * ldb) * 2 + ktb + scolS,
              &lds[65536 + d * BNB + c * 8192 + wid * 1024]);
  };

  stage(0, 0);
  int cur = 0;
#pragma unroll 2
  for (int t = 0; t < NT; ++t) {
    if (t + 1 < NT) stage(t + 1, cur ^ 1);
    __builtin_amdgcn_sched_barrier(0);
    if (t + 1 < NT) {
      if constexpr (NF == 4)
        asm volatile("s_waitcnt vmcnt(8)");  // tile t done; t+1's 8 in flight
      else
        asm volatile("s_waitcnt vmcnt(6)");
    } else {
      asm volatile("s_waitcnt vmcnt(0)");
    }
    __builtin_amdgcn_sched_barrier(0);
    __builtin_amdgcn_s_barrier();  // all waves see buf[cur] full
    __builtin_amdgcn_sched_barrier(0);
    {
      const int dA = cur * 32768, dB = 65536 + cur * BNB;
#pragma unroll
      for (int ks = 0; ks < 2; ++ks) {
        f16x8 ar[8], br[NF];
#pragma unroll
        for (int m = 0; m < 8; m++)
          ar[m] = *(const f16x8*)&lds[dA + (aoff[m] ^ (ks << 6))];
#pragma unroll
        for (int n = 0; n < NF; n++)
          br[n] = *(const f16x8*)&lds[dB + (boff[n] ^ (ks << 6))];
#pragma unroll
        for (int m = 0; m < 8; m++)
#pragma unroll
          for (int n = 0; n < NF; n++)
            acc[m][n] = __builtin_amdgcn_mfma_f32_16x16x32_f16(
                ar[m], br[n], acc[m][n], 0, 0, 0);
      }
    }
    __builtin_amdgcn_sched_barrier(0);
    __builtin_amdgcn_s_barrier();  // buf[cur] free for overwrite next iter
    __builtin_amdgcn_sched_barrier(0);
    cur ^= 1;
  }

#pragma unroll
  for (int m = 0; m < 8; m++) {
    const size_t row0 = bm + wr * 128 + m * 16 + fq * 4;
#pragma unroll
    for (int n = 0; n < NF; n++) {
      const size_t col = bn + wc * NF * 16 + n * 16 + fr;
      float bcol = (BIAS_MODE == 1) ? bias[col] : 0.f;
#pragma unroll
      for (int r = 0; r < 4; r++) {
        float val = acc[m][n][r];
        const size_t row = row0 + r;
        const size_t idx = row * (size_t)ldc + col;
        if (BIAS_MODE == 1) val += bcol;
        if (BIAS_MODE == 2) val += bias[row];
        if (RES) val += res[idx];
        if (OMODE == 0)
          ((float*)Cb)[idx] = val;
        else
          ((short*)Cb)[idx] = f2h(val);
      }
    }
  }
}

__global__ __launch_bounds__(256) void cvt_f32_f16(const float* __restrict__ s,
                                                   short* __restrict__ d, int n) {
  int i = (blockIdx.x * 256 + threadIdx.x) * 8;
  if (i >= n) return;
  const float4 a = *(const float4*)(s + i);
  const float4 b = *(const float4*)(s + i + 4);
  bf16x8 o;
  o[0] = f2h(a.x); o[1] = f2h(a.y); o[2] = f2h(a.z); o[3] = f2h(a.w);
  o[4] = f2h(b.x); o[5] = f2h(b.y); o[6] = f2h(b.z); o[7] = f2h(b.w);
  *(bf16x8*)(d + i) = o;
}

// one block per row of 4096 f16 scores; fp32 softmax; in-place f16 probs
__global__ __launch_bounds__(256) void softmax_rows(short* __restrict__ S) {
  const size_t row = blockIdx.x;
  short* rp = S + row * 4096;
  const int tid = threadIdx.x;
  const int lane = tid & 63, wid = tid >> 6;
  float v[16];
#pragma unroll
  for (int c = 0; c < 2; c++) {
    bf16x8 xv = *(const bf16x8*)(rp + (c * 256 + tid) * 8);
#pragma unroll
    for (int j = 0; j < 8; j++) v[c * 8 + j] = h2f(xv[j]);
  }
  float m = v[0];
#pragma unroll
  for (int i = 1; i < 16; i++) m = fmaxf(m, v[i]);
#pragma unroll
  for (int off = 32; off >= 1; off >>= 1) m = fmaxf(m, __shfl_xor(m, off));
  __shared__ float red[8];
  if (lane == 0) red[wid] = m;
  __syncthreads();
  m = fmaxf(fmaxf(red[0], red[1]), fmaxf(red[2], red[3]));
  float s = 0.f;
#pragma unroll
  for (int i = 0; i < 16; i++) {
    v[i] = __expf(v[i] - m);
    s += v[i];
  }
#pragma unroll
  for (int off = 32; off >= 1; off >>= 1) s += __shfl_xor(s, off);
  if (lane == 0) red[4 + wid] = s;
  __syncthreads();
  s = (red[4] + red[5]) + (red[6] + red[7]);
  const float rs = 1.0f / s;
#pragma unroll
  for (int c = 0; c < 2; c++) {
    bf16x8 o;
#pragma unroll
    for (int j = 0; j < 8; j++) o[j] = f2h(v[c * 8 + j] * rs);
    *(bf16x8*)(rp + (c * 256 + tid) * 8) = o;
  }
}

extern "C" void kernel_launch(void* const* d_in, const int* in_sizes, int n_in,
                              void* d_out, int out_size, void* d_ws,
                              size_t ws_size, hipStream_t stream) {
  const float* x   = (const float*)d_in[0];
  const float* thw = (const float*)d_in[1];
  const float* thb = (const float*)d_in[2];
  const float* phw = (const float*)d_in[3];
  const float* phb = (const float*)d_in[4];
  const float* gw  = (const float*)d_in[5];
  const float* gbi = (const float*)d_in[6];
  const float* Ww  = (const float*)d_in[7];
  const float* Wb  = (const float*)d_in[8];
  float* out = (float*)d_out;

  // B=4, N=4096, D=2048, E=1024.  ws footprint 184,557,568 B (proven size)
  char* ws = (char*)d_ws;
  short* xf   = (short*)(ws);                // 67,108,864 B (16384x2048 f16)
  short* wcat = (short*)(ws + 67108864);     //  8,388,608 B (theta|phi 2048x2048)
  short* gwb  = (short*)(ws + 75497472);     //  4,194,304 B (1024x2048)
  short* wWb  = (short*)(ws + 79691776);     //  4,194,304 B (2048x1024)
  float* bc   = (float*)(ws + 83886080);     //  8,192 B (theta_b|phi_b)
  short* tpf  = (short*)(ws + 83894272);     // 67,108,864 B (theta|phi; later y)
  short* gT   = (short*)(ws + 151003136);    // 33,554,432 B (4x1024x4096)
  short* sc   = (short*)(ws);                // 67,108,864 B (2x4096x4096, over xf)

  // 1) fp32 -> f16 conversions
  cvt_f32_f16<<<16384, 256, 0, stream>>>(x, xf, 33554432);
  cvt_f32_f16<<<1024, 256, 0, stream>>>(thw, wcat, 2097152);
  cvt_f32_f16<<<1024, 256, 0, stream>>>(phw, wcat + 2097152, 2097152);
  cvt_f32_f16<<<1024, 256, 0, stream>>>(gw, gwb, 2097152);
  cvt_f32_f16<<<1024, 256, 0, stream>>>(Ww, wWb, 2097152);
  hipMemcpyAsync(bc, thb, 4096, hipMemcpyDeviceToDevice, stream);
  hipMemcpyAsync(bc + 1024, phb, 4096, hipMemcpyDeviceToDevice, stream);

  // 2) proj: [theta|phi] = x @ wcat^T + bias   (16384 x 2048, K=2048)
  gemm256<4, 2048, 1, 1, 0><<<dim3(8, 64, 1), 512, 0, stream>>>(
      xf, 2048, 0L, wcat, 2048, 0L, tpf, 2048, 0L, bc, nullptr, 0L);

  // 3) gT[b] = g_w @ x_b^T + g_b[row]   (1024 x 4096 per batch, K=2048)
  gemm256<4, 2048, 1, 2, 0><<<dim3(16, 4, 4), 512, 0, stream>>>(
      gwb, 2048, 0L, xf, 2048, 8388608L, gT, 4096, 4194304L, gbi, nullptr, 0L);

  // 4) per batch-PAIR p: scores(z=2) -> softmax -> y(z=2) -> z(z=2)
  //    sc pair overlays xf (dead after gT); y overwrites consumed theta/phi.
  for (int p = 0; p < 2; ++p) {
    const short* tp = tpf + (size_t)p * 16777216;
    gemm256<4, 1024, 1, 0, 0><<<dim3(16, 16, 2), 512, 0, stream>>>(
        tp, 2048, 8388608L, tp + 1024, 2048, 8388608L,
        sc, 4096, 16777216L, nullptr, nullptr, 0L);
    softmax_rows<<<8192, 256, 0, stream>>>(sc);
    short* yp = tpf + (size_t)p * 16777216;  // pair-p theta/phi now dead
    gemm256<2, 4096, 1, 0, 0><<<dim3(8, 16, 2), 512, 0, stream>>>(
        sc, 4096, 16777216L, gT + (size_t)p * 8388608, 4096, 4194304L,
        yp, 1024, 4194304L, nullptr, nullptr, 0L);
    gemm256<4, 1024, 0, 1, 1><<<dim3(8, 16, 2), 512, 0, stream>>>(
        yp, 1024, 4194304L, wWb, 1024, 0L,
        out + (size_t)p * 16777216, 2048, 8388608L,
        Wb, x + (size_t)p * 16777216, 8388608L);
  }
}